// Round 2
// baseline (898.347 us; speedup 1.0000x reference)
//
#include <hip/hip_runtime.h>
#include <stdint.h>

typedef _Float16 half_t;
typedef __attribute__((ext_vector_type(4))) _Float16 half4;
typedef __attribute__((ext_vector_type(8))) _Float16 half8;
typedef __attribute__((ext_vector_type(4))) float f32x4;

#define N_TOK 8192
#define H_DIM 1024
#define D_DIM 512
#define NE 8
#define NL 3

// -------- async global->LDS, 16B per lane, linear dest --------
__device__ __forceinline__ void gload_lds16(const half_t* g, half_t* l) {
  __builtin_amdgcn_global_load_lds(
      (const __attribute__((address_space(1))) unsigned int*)g,
      (__attribute__((address_space(3))) unsigned int*)l, 16, 0, 0);
}

// -------- init: softmax over hierarchical weights + zero counters --------
__global__ void init_small(const float* __restrict__ w, float* __restrict__ hwp,
                           int* __restrict__ cnt) {
  const int t = threadIdx.x;
  if (t < NL * NE) cnt[t] = 0;
  if (t == 0) {
    float m = fmaxf(fmaxf(w[0], w[1]), w[2]);
    float e0 = expf(w[0] - m), e1 = expf(w[1] - m), e2 = expf(w[2] - m);
    float s = e0 + e1 + e2;
    hwp[0] = e0 / s; hwp[1] = e1 / s; hwp[2] = e2 / s;
  }
}

// -------- fp32 [R][C] -> f16 transposed [C][R], optional scaled-lo output --------
__global__ void transpose_cvt(const float* __restrict__ in, unsigned long long in_zs,
                              half_t* __restrict__ oh, half_t* __restrict__ ol,
                              unsigned long long out_zs, int R, int C) {
  __shared__ float tile[64][65];
  const float* src = in + (size_t)blockIdx.z * in_zs;
  const int rt = blockIdx.x * 64;
  const int ct = blockIdx.y * 64;
  const int tid = threadIdx.x;
  const int r = tid >> 2, c0 = (tid & 3) * 16;
  const float* p = src + (size_t)(rt + r) * C + ct + c0;
#pragma unroll
  for (int q = 0; q < 4; ++q) {
    float4 v = *(const float4*)(p + q * 4);
    tile[r][c0 + q * 4 + 0] = v.x;
    tile[r][c0 + q * 4 + 1] = v.y;
    tile[r][c0 + q * 4 + 2] = v.z;
    tile[r][c0 + q * 4 + 3] = v.w;
  }
  __syncthreads();
  const int nl = tid >> 2, k0 = (tid & 3) * 16;
  half8 hv0, hv1, lv0, lv1;
#pragma unroll
  for (int i = 0; i < 16; ++i) {
    float v = tile[k0 + i][nl];
    half_t h = (half_t)v;
    half_t lo = (half_t)((v - (float)h) * 2048.f);
    if (i < 8) { hv0[i] = h; lv0[i] = lo; } else { hv1[i - 8] = h; lv1[i - 8] = lo; }
  }
  half_t* dst = oh + (size_t)blockIdx.z * out_zs + (size_t)(ct + nl) * R + rt + k0;
  *(half8*)dst = hv0;
  *(half8*)(dst + 8) = hv1;
  if (ol) {
    half_t* dstl = ol + (size_t)blockIdx.z * out_zs + (size_t)(ct + nl) * R + rt + k0;
    *(half8*)dstl = lv0;
    *(half8*)(dstl + 8) = lv1;
  }
}

// -------- fp32 x -> f16 hi + scaled lo --------
__global__ void cvt_x_hilo(const float* __restrict__ in, half_t* __restrict__ oh,
                           half_t* __restrict__ ol, int n4) {
  int i = blockIdx.x * blockDim.x + threadIdx.x;
  if (i < n4) {
    float4 v = ((const float4*)in)[i];
    float vv[4] = {v.x, v.y, v.z, v.w};
    half4 hv, lv;
#pragma unroll
    for (int j = 0; j < 4; ++j) {
      half_t h = (half_t)vv[j];
      hv[j] = h;
      lv[j] = (half_t)((vv[j] - (float)h) * 2048.f);
    }
    ((half4*)oh)[i] = hv;
    ((half4*)ol)[i] = lv;
  }
}

// -------- router GEMM: h = relu(x @ w1 + b1), fp16-split 3-pass MFMA --------
// A: x hi/lo [8192][1024]; B: w1^T hi/lo [512][1024]; BM=128 BN=64 BK=32
__global__ __launch_bounds__(256, 2) void routing_gemm(
    const half_t* __restrict__ xh, const half_t* __restrict__ xl,
    const half_t* __restrict__ wh, const half_t* __restrict__ wl,
    const float* __restrict__ b1, float* __restrict__ hout) {
  __shared__ __align__(16) half_t Ah[128 * 32], Al[128 * 32], Bh[64 * 32], Bl[64 * 32];
  const int tid = threadIdx.x;
  const int lane = tid & 63;
  const int wv = tid >> 6;
  const int wm = wv >> 1, wn = wv & 1;
  const int mt = blockIdx.x, nt = blockIdx.y;

  const int srow = tid >> 2;
  const int skc = (tid & 3) * 8;
  const size_t abase = (size_t)(mt * 128 + srow) * H_DIM + skc;
  const half_t* gAh = xh + abase;
  const half_t* gAl = xl + abase;
  const size_t bbase = (size_t)(nt * 64 + srow) * H_DIM + skc;
  const half_t* gBh = wh + bbase;
  const half_t* gBl = wl + bbase;

  half_t* lAh0 = &Ah[tid * 8]; half_t* lAh1 = &Ah[2048 + tid * 8];
  half_t* lAl0 = &Al[tid * 8]; half_t* lAl1 = &Al[2048 + tid * 8];
  half_t* lBh0 = &Bh[tid * 8];
  half_t* lBl0 = &Bl[tid * 8];

  f32x4 accM[4][2], accX[4][2];
#pragma unroll
  for (int m = 0; m < 4; ++m)
#pragma unroll
    for (int n = 0; n < 2; ++n) {
      accM[m][n] = {0.f, 0.f, 0.f, 0.f};
      accX[m][n] = {0.f, 0.f, 0.f, 0.f};
    }

  const int fr = lane & 15, fg = lane >> 4;
  const int aoff = (wm * 64 + fr) * 32 + fg * 8;
  const int boff = (wn * 32 + fr) * 32 + fg * 8;

  for (int kk = 0; kk < H_DIM / 32; ++kk) {
    const int go = kk * 32;
    gload_lds16(gAh + go, lAh0);
    gload_lds16(gAh + go + (size_t)64 * H_DIM, lAh1);
    gload_lds16(gAl + go, lAl0);
    gload_lds16(gAl + go + (size_t)64 * H_DIM, lAl1);
    gload_lds16(gBh + go, lBh0);
    gload_lds16(gBl + go, lBl0);
    __syncthreads();
    half8 a_h[4], a_l[4], b_h[2], b_l[2];
#pragma unroll
    for (int m = 0; m < 4; ++m) {
      a_h[m] = *(const half8*)&Ah[aoff + m * 16 * 32];
      a_l[m] = *(const half8*)&Al[aoff + m * 16 * 32];
    }
#pragma unroll
    for (int n = 0; n < 2; ++n) {
      b_h[n] = *(const half8*)&Bh[boff + n * 16 * 32];
      b_l[n] = *(const half8*)&Bl[boff + n * 16 * 32];
    }
#pragma unroll
    for (int m = 0; m < 4; ++m)
#pragma unroll
      for (int n = 0; n < 2; ++n) {
        accM[m][n] = __builtin_amdgcn_mfma_f32_16x16x32_f16(a_h[m], b_h[n], accM[m][n], 0, 0, 0);
        accX[m][n] = __builtin_amdgcn_mfma_f32_16x16x32_f16(a_h[m], b_l[n], accX[m][n], 0, 0, 0);
        accX[m][n] = __builtin_amdgcn_mfma_f32_16x16x32_f16(a_l[m], b_h[n], accX[m][n], 0, 0, 0);
      }
    __syncthreads();
  }

  const float inv = 1.0f / 2048.0f;
#pragma unroll
  for (int m = 0; m < 4; ++m) {
    const int row0 = mt * 128 + wm * 64 + m * 16 + fg * 4;
#pragma unroll
    for (int n = 0; n < 2; ++n) {
      const int col = nt * 64 + wn * 32 + n * 16 + fr;
      const float bv = b1[col];
#pragma unroll
      for (int r = 0; r < 4; ++r) {
        float v = accM[m][n][r] + accX[m][n][r] * inv + bv;
        hout[(size_t)(row0 + r) * D_DIM + col] = fmaxf(v, 0.f);
      }
    }
  }
}

// -------- logits + argmax + per-expert count; one wave per token --------
__global__ void logits_argmax(const float* __restrict__ hbuf, const float* __restrict__ w2,
                              const float* __restrict__ b2, int* __restrict__ eidx,
                              int* __restrict__ cnt) {
  const int tid = threadIdx.x, lane = tid & 63, wv = tid >> 6;
  const int t = blockIdx.x * 4 + wv;
  const float* hr = hbuf + (size_t)t * D_DIM;
  float4 h0 = *(const float4*)(hr + lane * 8);
  float4 h1 = *(const float4*)(hr + lane * 8 + 4);
  float p[8] = {0, 0, 0, 0, 0, 0, 0, 0};
  const float* wr = w2 + (size_t)lane * 8 * 8;
  float hv[8] = {h0.x, h0.y, h0.z, h0.w, h1.x, h1.y, h1.z, h1.w};
#pragma unroll
  for (int j = 0; j < 8; ++j) {
    float4 wa = *(const float4*)(wr + j * 8);
    float4 wb = *(const float4*)(wr + j * 8 + 4);
    p[0] += hv[j] * wa.x; p[1] += hv[j] * wa.y; p[2] += hv[j] * wa.z; p[3] += hv[j] * wa.w;
    p[4] += hv[j] * wb.x; p[5] += hv[j] * wb.y; p[6] += hv[j] * wb.z; p[7] += hv[j] * wb.w;
  }
#pragma unroll
  for (int o = 32; o > 0; o >>= 1) {
#pragma unroll
    for (int e = 0; e < 8; ++e) p[e] += __shfl_xor(p[e], o, 64);
  }
  if (lane == 0) {
    int best = 0;
    float bvv = p[0] + b2[0];
#pragma unroll
    for (int e = 1; e < 8; ++e) {
      float v = p[e] + b2[e];
      if (v > bvv) { bvv = v; best = e; }
    }
    eidx[t] = best;
    atomicAdd(&cnt[best], 1);
  }
}

__global__ void scan8(const int* __restrict__ cnt, int* __restrict__ offs, int* __restrict__ cur) {
  if (threadIdx.x == 0) {
    int a = 0;
    for (int i = 0; i < 8; ++i) { offs[i] = a; cur[i] = a; a += cnt[i]; }
    offs[8] = a;
  }
}

__global__ void scatter_perm(const int* __restrict__ eidx, int* __restrict__ cur,
                             int* __restrict__ perm) {
  int t = blockIdx.x * blockDim.x + threadIdx.x;
  if (t < N_TOK) {
    int p = atomicAdd(&cur[eidx[t]], 1);
    perm[p] = t;
  }
}

// -------- expert GEMM: out = a_e*(x @ W[e] + b[e]); fused epilogue --------
// gathered A rows via perm; B = W^T f16 hi/lo [1024][1024]; BM=128 BN=64 BK=32
// SPLIT=1: 3-pass fp16-split (fp32-accurate, writes next-level x hi/lo)
// SPLIT=0: 1-pass hi-only (last level, output-only)
template <int SPLIT>
__global__ __launch_bounds__(256, 2) void expert_gemm(
    const half_t* __restrict__ xh, const half_t* __restrict__ xl,
    const half_t* __restrict__ Wth, const half_t* __restrict__ Wtl,
    const float* __restrict__ bb, const float* __restrict__ asg,
    const int* __restrict__ perm, const int* __restrict__ offs,
    const float* __restrict__ hwp, const int lvl,
    float* __restrict__ dout, half_t* __restrict__ xnh, half_t* __restrict__ xnl) {
  __shared__ __align__(16) half_t Ah[128 * 32], Bh[64 * 32];
  __shared__ __align__(16) half_t Al[SPLIT ? 128 * 32 : 8], Bl[SPLIT ? 64 * 32 : 8];
  __shared__ int toks[128];
  const int tid = threadIdx.x;
  int e = -1, base = 0, nrows = 0, acc_t = 0;
#pragma unroll
  for (int i = 0; i < 8; ++i) {
    int s = offs[i], t2 = offs[i + 1];
    int ntl = (t2 - s + 127) >> 7;
    if (e < 0 && (int)blockIdx.x < acc_t + ntl) {
      e = i;
      base = s + ((int)blockIdx.x - acc_t) * 128;
      nrows = t2 - base;
      if (nrows > 128) nrows = 128;
    }
    acc_t += ntl;
  }
  if (e < 0) return;
  if (tid < 128) toks[tid] = (tid < nrows) ? perm[base + tid] : perm[base];
  __syncthreads();
  const int srow = tid >> 2, skc = (tid & 3) * 8;
  const int tokA0 = toks[srow];
  const int tokA1 = toks[64 + srow];
  const half_t* gAh0 = xh + (size_t)tokA0 * H_DIM + skc;
  const half_t* gAh1 = xh + (size_t)tokA1 * H_DIM + skc;
  const half_t* gAl0 = SPLIT ? (xl + (size_t)tokA0 * H_DIM + skc) : nullptr;
  const half_t* gAl1 = SPLIT ? (xl + (size_t)tokA1 * H_DIM + skc) : nullptr;
  const size_t boffg = (size_t)e * H_DIM * H_DIM + (size_t)(blockIdx.y * 64 + srow) * H_DIM + skc;
  const half_t* gBh = Wth + boffg;
  const half_t* gBl = SPLIT ? (Wtl + boffg) : nullptr;
  half_t* lAh0 = &Ah[tid * 8]; half_t* lAh1 = &Ah[2048 + tid * 8];
  half_t* lBh = &Bh[tid * 8];
  half_t* lAl0 = &Al[SPLIT ? tid * 8 : 0]; half_t* lAl1 = &Al[SPLIT ? 2048 + tid * 8 : 0];
  half_t* lBl = &Bl[SPLIT ? tid * 8 : 0];

  f32x4 accM[4][2], accX[4][2];
#pragma unroll
  for (int m = 0; m < 4; ++m)
#pragma unroll
    for (int n = 0; n < 2; ++n) {
      accM[m][n] = {0.f, 0.f, 0.f, 0.f};
      accX[m][n] = {0.f, 0.f, 0.f, 0.f};
    }

  const int lane = tid & 63, wv = tid >> 6, wm = wv >> 1, wn = wv & 1;
  const int fr = lane & 15, fg = lane >> 4;
  const int aoff = (wm * 64 + fr) * 32 + fg * 8;
  const int boff = (wn * 32 + fr) * 32 + fg * 8;

  for (int kk = 0; kk < H_DIM / 32; ++kk) {
    const int go = kk * 32;
    gload_lds16(gAh0 + go, lAh0);
    gload_lds16(gAh1 + go, lAh1);
    gload_lds16(gBh + go, lBh);
    if (SPLIT) {
      gload_lds16(gAl0 + go, lAl0);
      gload_lds16(gAl1 + go, lAl1);
      gload_lds16(gBl + go, lBl);
    }
    __syncthreads();
    half8 a_h[4], b_h[2], a_l[4], b_l[2];
#pragma unroll
    for (int m = 0; m < 4; ++m) {
      a_h[m] = *(const half8*)&Ah[aoff + m * 16 * 32];
      if (SPLIT) a_l[m] = *(const half8*)&Al[aoff + m * 16 * 32];
    }
#pragma unroll
    for (int n = 0; n < 2; ++n) {
      b_h[n] = *(const half8*)&Bh[boff + n * 16 * 32];
      if (SPLIT) b_l[n] = *(const half8*)&Bl[boff + n * 16 * 32];
    }
#pragma unroll
    for (int m = 0; m < 4; ++m)
#pragma unroll
      for (int n = 0; n < 2; ++n) {
        accM[m][n] = __builtin_amdgcn_mfma_f32_16x16x32_f16(a_h[m], b_h[n], accM[m][n], 0, 0, 0);
        if (SPLIT) {
          accX[m][n] = __builtin_amdgcn_mfma_f32_16x16x32_f16(a_h[m], b_l[n], accX[m][n], 0, 0, 0);
          accX[m][n] = __builtin_amdgcn_mfma_f32_16x16x32_f16(a_l[m], b_h[n], accX[m][n], 0, 0, 0);
        }
      }
    __syncthreads();
  }

  const float ae = asg[e];
  const float hwv = hwp[lvl];
  const float inv = 1.0f / 2048.0f;
  const bool first = (lvl == 0);
#pragma unroll
  for (int m = 0; m < 4; ++m) {
    const int rl0 = wm * 64 + m * 16 + fg * 4;
#pragma unroll
    for (int n = 0; n < 2; ++n) {
      const int col = blockIdx.y * 64 + wn * 32 + n * 16 + fr;
      const float bbv = bb[(size_t)e * H_DIM + col];
#pragma unroll
      for (int r = 0; r < 4; ++r) {
        const int rl = rl0 + r;
        if (rl < nrows) {
          const int tok = toks[rl];
          float s = accM[m][n][r] + bbv;
          if (SPLIT) s += accX[m][n][r] * inv;
          const float o = ae * s;
          const size_t idx = (size_t)tok * H_DIM + col;
          const float fo = hwv * o;
          if (first) dout[idx] = fo; else dout[idx] += fo;
          if (SPLIT) {
            half_t hv = (half_t)o;
            xnh[idx] = hv;
            xnl[idx] = (half_t)((o - (float)hv) * 2048.f);
          }
        }
      }
    }
  }
}

extern "C" void kernel_launch(void* const* d_in, const int* in_sizes, int n_in,
                              void* d_out, int out_size, void* d_ws, size_t ws_size,
                              hipStream_t stream) {
  const float* hs  = (const float*)d_in[0];   // (2,4096,1024)
  const float* w1  = (const float*)d_in[1];   // (3,1024,512)
  const float* b1  = (const float*)d_in[2];   // (3,512)
  const float* w2  = (const float*)d_in[3];   // (3,512,8)
  const float* b2  = (const float*)d_in[4];   // (3,8)
  const float* lea = (const float*)d_in[5];   // (3,8)
  const float* hww = (const float*)d_in[6];   // (3,)
  const float* Wb  = (const float*)d_in[7];   // (3,8,1024,1024)
  const float* bb  = (const float*)d_in[8];   // (3,8,1024)
  float* outp = (float*)d_out;

  char* ws = (char*)d_ws;
  size_t off = 0;
  half_t* Wth  = (half_t*)(ws + off); off += (size_t)NE * H_DIM * H_DIM * 2;   // 16.8MB (per-level, reused)
  half_t* Wtl  = (half_t*)(ws + off); off += (size_t)NE * H_DIM * H_DIM * 2;   // 16.8MB
  half_t* w1th = (half_t*)(ws + off); off += (size_t)NL * D_DIM * H_DIM * 2;
  half_t* w1tl = (half_t*)(ws + off); off += (size_t)NL * D_DIM * H_DIM * 2;
  half_t* xh0  = (half_t*)(ws + off); off += (size_t)N_TOK * H_DIM * 2;
  half_t* xl0  = (half_t*)(ws + off); off += (size_t)N_TOK * H_DIM * 2;
  half_t* xh1  = (half_t*)(ws + off); off += (size_t)N_TOK * H_DIM * 2;
  half_t* xl1  = (half_t*)(ws + off); off += (size_t)N_TOK * H_DIM * 2;
  float*  hbuf = (float*)(ws + off);  off += (size_t)N_TOK * D_DIM * 4;
  int*    eidx = (int*)(ws + off);    off += (size_t)N_TOK * 4;
  int*    perm = (int*)(ws + off);    off += (size_t)N_TOK * 4;
  int*    cnt  = (int*)(ws + off);    off += (size_t)NL * NE * 4;
  int*    offs = (int*)(ws + off);    off += (size_t)NL * (NE + 1) * 4;
  int*    cur  = (int*)(ws + off);    off += (size_t)NL * NE * 4;
  float*  hwp  = (float*)(ws + off);  off += 16;

  init_small<<<1, 64, 0, stream>>>(hww, hwp, cnt);
  transpose_cvt<<<dim3(16, 8, NL), 256, 0, stream>>>(
      w1, (unsigned long long)H_DIM * D_DIM, w1th, w1tl,
      (unsigned long long)D_DIM * H_DIM, H_DIM, D_DIM);
  cvt_x_hilo<<<(N_TOK * H_DIM / 4 + 255) / 256, 256, 0, stream>>>(
      hs, xh0, xl0, N_TOK * H_DIM / 4);

  for (int l = 0; l < NL; ++l) {
    const half_t* xch = (l & 1) ? xh1 : xh0;
    const half_t* xcl = (l & 1) ? xl1 : xl0;
    half_t* xnh = (l == 2) ? (half_t*)nullptr : ((l & 1) ? xh0 : xh1);
    half_t* xnl = (l == 2) ? (half_t*)nullptr : ((l & 1) ? xl0 : xl1);
    // convert this level's W_base (hi always; lo only when split needed)
    transpose_cvt<<<dim3(16, 16, NE), 256, 0, stream>>>(
        Wb + (size_t)l * NE * H_DIM * H_DIM, (unsigned long long)H_DIM * H_DIM,
        Wth, (l < 2) ? Wtl : (half_t*)nullptr,
        (unsigned long long)H_DIM * H_DIM, H_DIM, H_DIM);
    routing_gemm<<<dim3(64, 8), 256, 0, stream>>>(
        xch, xcl, w1th + (size_t)l * D_DIM * H_DIM, w1tl + (size_t)l * D_DIM * H_DIM,
        b1 + l * D_DIM, hbuf);
    logits_argmax<<<N_TOK / 4, 256, 0, stream>>>(
        hbuf, w2 + (size_t)l * D_DIM * NE, b2 + l * NE, eidx, cnt + l * NE);
    scan8<<<1, 64, 0, stream>>>(cnt + l * NE, offs + l * (NE + 1), cur + l * NE);
    scatter_perm<<<N_TOK / 256, 256, 0, stream>>>(eidx, cur + l * NE, perm);
    if (l < 2) {
      expert_gemm<1><<<dim3(72, 16), 256, 0, stream>>>(
          xch, xcl, Wth, Wtl, bb + (size_t)l * NE * H_DIM,
          lea + l * NE, perm, offs + l * (NE + 1), hwp, l, outp, xnh, xnl);
    } else {
      expert_gemm<0><<<dim3(72, 16), 256, 0, stream>>>(
          xch, (const half_t*)nullptr, Wth, (const half_t*)nullptr,
          bb + (size_t)l * NE * H_DIM,
          lea + l * NE, perm, offs + l * (NE + 1), hwp, l, outp,
          (half_t*)nullptr, (half_t*)nullptr);
    }
  }
}